// Round 2
// baseline (1518.781 us; speedup 1.0000x reference)
//
#include <hip/hip_runtime.h>

#define TT 512
#define NB 128   // batch
#define DD 128
#define HH 64
#define CC 45

__device__ __forceinline__ float sigf(float x) { return 1.0f / (1.0f + __expf(-x)); }

// ---------------------------------------------------------------------------
// GEMM: Cout[m][0:512] = A[m][0:128] @ [Wf | Wb] + [biasf | biasb]
// A: [65536][128] row-major. Wf/Wb: [128][256] row-major. Cout: [65536][512].
// BM=128, BN=128, BK=32, 256 threads, 8x8 accumulation per thread. f32 VALU.
// ---------------------------------------------------------------------------
__global__ __launch_bounds__(256) void gemm_xz(
    const float* __restrict__ A, const float* __restrict__ Wf,
    const float* __restrict__ Wb, const float* __restrict__ biasf,
    const float* __restrict__ biasb, float* __restrict__ Cout)
{
    __shared__ float As[32][132];   // [k][m], padded
    __shared__ float Bs[32][132];   // [k][n], padded
    const int tid = threadIdx.x;
    const int m0 = blockIdx.x * 128;
    const int n0 = blockIdx.y * 128;          // global col in [0,512)
    const float* W   = (n0 < 256) ? Wf : Wb;
    const float* bia = (n0 < 256) ? biasf : biasb;
    const int nc0 = n0 & 255;

    const int ty = tid >> 4, tx = tid & 15;
    const int arow = tid >> 3, akv = (tid & 7) << 2;
    const int bkr  = tid >> 5, bnv = (tid & 31) << 2;

    float acc[8][8];
    #pragma unroll
    for (int i = 0; i < 8; ++i)
        #pragma unroll
        for (int j = 0; j < 8; ++j) acc[i][j] = 0.f;

    for (int k0 = 0; k0 < 128; k0 += 32) {
        #pragma unroll
        for (int rr = 0; rr < 4; ++rr) {
            const int r = arow + rr * 32;
            const float4 av = *(const float4*)&A[(size_t)(m0 + r) * 128 + k0 + akv];
            As[akv + 0][r] = av.x; As[akv + 1][r] = av.y;
            As[akv + 2][r] = av.z; As[akv + 3][r] = av.w;
        }
        #pragma unroll
        for (int rr = 0; rr < 4; ++rr) {
            const int kr = bkr + rr * 8;
            *(float4*)&Bs[kr][bnv] =
                *(const float4*)&W[(size_t)(k0 + kr) * 256 + nc0 + bnv];
        }
        __syncthreads();
        #pragma unroll
        for (int k = 0; k < 32; ++k) {
            float av[8], bv[8];
            *(float4*)&av[0] = *(const float4*)&As[k][ty * 8];
            *(float4*)&av[4] = *(const float4*)&As[k][ty * 8 + 4];
            *(float4*)&bv[0] = *(const float4*)&Bs[k][tx * 8];
            *(float4*)&bv[4] = *(const float4*)&Bs[k][tx * 8 + 4];
            #pragma unroll
            for (int i = 0; i < 8; ++i)
                #pragma unroll
                for (int j = 0; j < 8; ++j)
                    acc[i][j] = __fmaf_rn(av[i], bv[j], acc[i][j]);
        }
        __syncthreads();
    }
    #pragma unroll
    for (int i = 0; i < 8; ++i) {
        const size_t rbase = (size_t)(m0 + ty * 8 + i) * 512 + n0 + tx * 8;
        float4 o;
        o.x = acc[i][0] + bia[nc0 + tx * 8 + 0];
        o.y = acc[i][1] + bia[nc0 + tx * 8 + 1];
        o.z = acc[i][2] + bia[nc0 + tx * 8 + 2];
        o.w = acc[i][3] + bia[nc0 + tx * 8 + 3];
        *(float4*)&Cout[rbase] = o;
        o.x = acc[i][4] + bia[nc0 + tx * 8 + 4];
        o.y = acc[i][5] + bia[nc0 + tx * 8 + 5];
        o.z = acc[i][6] + bia[nc0 + tx * 8 + 6];
        o.w = acc[i][7] + bia[nc0 + tx * 8 + 7];
        *(float4*)&Cout[rbase + 4] = o;
    }
}

// ---------------------------------------------------------------------------
// LSTM recurrence, single-wave-per-chain. 256 blocks x 64 threads.
// Lane l owns h-column l: holds U[:,l], U[:,64+l], U[:,128+l], U[:,192+l]
// in 256 VGPRs, computes all 4 gate pre-activations + state update itself.
// h broadcast via 64-float LDS buffer. Zero barriers in the step loop:
// one wave executes in lockstep and same-wave LDS ops complete in order,
// so ds_write(h) -> ds_read(h) next step is hazard-free.
// xz: [B*T][512] (dir offset 256). hout: [B*T][128] (fwd 0-63, bwd 64-127).
// ---------------------------------------------------------------------------
__global__ __launch_bounds__(64, 1) void lstm_rec1w(
    const float* __restrict__ xz, const float* __restrict__ Uf,
    const float* __restrict__ Ub, float* __restrict__ hout)
{
    const int b   = blockIdx.x & 127;
    const int dir = blockIdx.x >> 7;
    const int l   = threadIdx.x;          // 0..63
    const float* U = dir ? Ub : Uf;

    __shared__ float h_lds[64];

    float ui[64], uf[64], ug[64], uo[64]; // 256 VGPRs (launch_bounds(64,1))
    #pragma unroll
    for (int k = 0; k < 64; ++k) {
        const float* Urow = U + (size_t)k * 256;
        ui[k] = Urow[l];
        uf[k] = Urow[64 + l];
        ug[k] = Urow[128 + l];
        uo[k] = Urow[192 + l];
    }

    h_lds[l] = 0.f;
    float c = 0.f;
    __syncthreads();

    const float* xzb = xz + (size_t)b * TT * 512 + (size_t)dir * 256 + l;
    float*       hob = hout + (size_t)b * TT * 128 + (size_t)dir * 64 + l;

    int trow = dir ? (TT - 1) : 0;
    const int tstep = dir ? -1 : 1;
    const float* xr0 = xzb + (size_t)trow * 512;
    float xi = xr0[0], xf = xr0[64], xg = xr0[128], xo = xr0[192];

    for (int s = 0; s < TT; ++s) {
        const int trn = trow + tstep;
        float ni = 0.f, nf = 0.f, ng = 0.f, no = 0.f;
        if (s + 1 < TT) {                       // prefetch next step's x
            const float* xr = xzb + (size_t)trn * 512;
            ni = xr[0]; nf = xr[64]; ng = xr[128]; no = xr[192];
        }

        float zi = xi, zf = xf, zg = xg, zo = xo;
        #pragma unroll
        for (int k4 = 0; k4 < 64; k4 += 4) {
            const float4 hv = *(const float4*)&h_lds[k4];   // broadcast read
            zi = __fmaf_rn(hv.x, ui[k4 + 0], zi);
            zf = __fmaf_rn(hv.x, uf[k4 + 0], zf);
            zg = __fmaf_rn(hv.x, ug[k4 + 0], zg);
            zo = __fmaf_rn(hv.x, uo[k4 + 0], zo);
            zi = __fmaf_rn(hv.y, ui[k4 + 1], zi);
            zf = __fmaf_rn(hv.y, uf[k4 + 1], zf);
            zg = __fmaf_rn(hv.y, ug[k4 + 1], zg);
            zo = __fmaf_rn(hv.y, uo[k4 + 1], zo);
            zi = __fmaf_rn(hv.z, ui[k4 + 2], zi);
            zf = __fmaf_rn(hv.z, uf[k4 + 2], zf);
            zg = __fmaf_rn(hv.z, ug[k4 + 2], zg);
            zo = __fmaf_rn(hv.z, uo[k4 + 2], zo);
            zi = __fmaf_rn(hv.w, ui[k4 + 3], zi);
            zf = __fmaf_rn(hv.w, uf[k4 + 3], zf);
            zg = __fmaf_rn(hv.w, ug[k4 + 3], zg);
            zo = __fmaf_rn(hv.w, uo[k4 + 3], zo);
        }

        c = sigf(zf) * c + sigf(zi) * fmaxf(zg, 0.f);
        const float h = sigf(zo) * fmaxf(c, 0.f);

        __builtin_amdgcn_wave_barrier();   // fence compiler motion around LDS swap
        h_lds[l] = h;                      // same-wave LDS in-order: no s_barrier
        __builtin_amdgcn_wave_barrier();

        hob[(size_t)trow * 128] = h;

        xi = ni; xf = nf; xg = ng; xo = no;
        trow = trn;
    }
}

// ---------------------------------------------------------------------------
// Dense + softmax: out[m][c] = softmax_c( h2[m][:] @ Wd[:,c] + bd[c] )
// ---------------------------------------------------------------------------
__global__ __launch_bounds__(256) void dense_softmax(
    const float* __restrict__ h2, const float* __restrict__ Wd,
    const float* __restrict__ bd, float* __restrict__ out)
{
    __shared__ float Wl[128 * 45];
    __shared__ float bl[48];
    __shared__ float hrow[4][128];
    const int tid = threadIdx.x;
    for (int i = tid; i < 128 * 45; i += 256) Wl[i] = Wd[i];
    if (tid < 45) bl[tid] = bd[tid];
    __syncthreads();

    const int w = tid >> 6, l = tid & 63;
    const size_t row0 = (size_t)blockIdx.x * 64;
    for (int rr = 0; rr < 16; ++rr) {
        const size_t m = row0 + (size_t)rr * 4 + w;
        const float2 hv = *(const float2*)&h2[m * 128 + l * 2];
        hrow[w][l * 2] = hv.x;
        hrow[w][l * 2 + 1] = hv.y;
        __syncthreads();
        float lg = -3.0e38f;
        if (l < CC) {
            lg = bl[l];
            #pragma unroll 8
            for (int k = 0; k < 128; ++k) lg = __fmaf_rn(hrow[w][k], Wl[k * 45 + l], lg);
        }
        float mx = lg;
        #pragma unroll
        for (int off = 32; off >= 1; off >>= 1) mx = fmaxf(mx, __shfl_xor(mx, off));
        const float e = (l < CC) ? __expf(lg - mx) : 0.f;
        float sm = e;
        #pragma unroll
        for (int off = 32; off >= 1; off >>= 1) sm += __shfl_xor(sm, off);
        if (l < CC) out[m * 45 + l] = e / sm;
        __syncthreads();
    }
}

// ---------------------------------------------------------------------------
extern "C" void kernel_launch(void* const* d_in, const int* in_sizes, int n_in,
                              void* d_out, int out_size, void* d_ws, size_t ws_size,
                              hipStream_t stream)
{
    const float* x   = (const float*)d_in[0];
    const float* W1f = (const float*)d_in[1];
    const float* U1f = (const float*)d_in[2];
    const float* b1f = (const float*)d_in[3];
    const float* W1b = (const float*)d_in[4];
    const float* U1b = (const float*)d_in[5];
    const float* b1b = (const float*)d_in[6];
    const float* W2f = (const float*)d_in[7];
    const float* U2f = (const float*)d_in[8];
    const float* b2f = (const float*)d_in[9];
    const float* W2b = (const float*)d_in[10];
    const float* U2b = (const float*)d_in[11];
    const float* b2b = (const float*)d_in[12];
    const float* Wd  = (const float*)d_in[13];
    const float* bd  = (const float*)d_in[14];

    // Workspace layout (160 MiB):
    //   xz : 65536 x 512 f32 = 128 MiB   (reused by layer 1 and layer 2)
    //   h  : 65536 x 128 f32 =  32 MiB   (h1, then overwritten by h2)
    float* xz = (float*)d_ws;
    float* h  = (float*)((char*)d_ws + (size_t)65536 * 512 * 4);

    const dim3 gemm_grid(512, 4);      // 65536/128 m-tiles, 512/128 n-tiles
    const dim3 rec_grid(256);          // 128 batch x 2 directions
    const dim3 dense_grid(1024);       // 65536/64 rows

    // Layer 1
    gemm_xz<<<gemm_grid, dim3(256), 0, stream>>>(x, W1f, W1b, b1f, b1b, xz);
    lstm_rec1w<<<rec_grid, dim3(64), 0, stream>>>(xz, U1f, U1b, h);
    // Layer 2
    gemm_xz<<<gemm_grid, dim3(256), 0, stream>>>(h, W2f, W2b, b2f, b2b, xz);
    lstm_rec1w<<<rec_grid, dim3(64), 0, stream>>>(xz, U2f, U2b, h);
    // Head
    dense_softmax<<<dense_grid, dim3(256), 0, stream>>>(h, Wd, bd, (float*)d_out);
}

// Round 3
// 827.639 us; speedup vs baseline: 1.8351x; 1.8351x over previous
//
#include <hip/hip_runtime.h>

#define TT 512
#define NB 128   // batch
#define DD 128
#define HH 64
#define CC 45

__device__ __forceinline__ float sigf(float x) { return 1.0f / (1.0f + __expf(-x)); }

// ---------------------------------------------------------------------------
// GEMM: Cout[m][0:512] = A[m][0:128] @ [Wf | Wb] + [biasf | biasb]
// A: [65536][128] row-major. Wf/Wb: [128][256] row-major. Cout: [65536][512].
// BM=128, BN=128, BK=32, 256 threads, 8x8 accumulation per thread. f32 VALU.
// ---------------------------------------------------------------------------
__global__ __launch_bounds__(256) void gemm_xz(
    const float* __restrict__ A, const float* __restrict__ Wf,
    const float* __restrict__ Wb, const float* __restrict__ biasf,
    const float* __restrict__ biasb, float* __restrict__ Cout)
{
    __shared__ float As[32][132];   // [k][m], padded
    __shared__ float Bs[32][132];   // [k][n], padded
    const int tid = threadIdx.x;
    const int m0 = blockIdx.x * 128;
    const int n0 = blockIdx.y * 128;          // global col in [0,512)
    const float* W   = (n0 < 256) ? Wf : Wb;
    const float* bia = (n0 < 256) ? biasf : biasb;
    const int nc0 = n0 & 255;

    const int ty = tid >> 4, tx = tid & 15;
    const int arow = tid >> 3, akv = (tid & 7) << 2;
    const int bkr  = tid >> 5, bnv = (tid & 31) << 2;

    float acc[8][8];
    #pragma unroll
    for (int i = 0; i < 8; ++i)
        #pragma unroll
        for (int j = 0; j < 8; ++j) acc[i][j] = 0.f;

    for (int k0 = 0; k0 < 128; k0 += 32) {
        #pragma unroll
        for (int rr = 0; rr < 4; ++rr) {
            const int r = arow + rr * 32;
            const float4 av = *(const float4*)&A[(size_t)(m0 + r) * 128 + k0 + akv];
            As[akv + 0][r] = av.x; As[akv + 1][r] = av.y;
            As[akv + 2][r] = av.z; As[akv + 3][r] = av.w;
        }
        #pragma unroll
        for (int rr = 0; rr < 4; ++rr) {
            const int kr = bkr + rr * 8;
            *(float4*)&Bs[kr][bnv] =
                *(const float4*)&W[(size_t)(k0 + kr) * 256 + nc0 + bnv];
        }
        __syncthreads();
        #pragma unroll
        for (int k = 0; k < 32; ++k) {
            float av[8], bv[8];
            *(float4*)&av[0] = *(const float4*)&As[k][ty * 8];
            *(float4*)&av[4] = *(const float4*)&As[k][ty * 8 + 4];
            *(float4*)&bv[0] = *(const float4*)&Bs[k][tx * 8];
            *(float4*)&bv[4] = *(const float4*)&Bs[k][tx * 8 + 4];
            #pragma unroll
            for (int i = 0; i < 8; ++i)
                #pragma unroll
                for (int j = 0; j < 8; ++j)
                    acc[i][j] = __fmaf_rn(av[i], bv[j], acc[i][j]);
        }
        __syncthreads();
    }
    #pragma unroll
    for (int i = 0; i < 8; ++i) {
        const size_t rbase = (size_t)(m0 + ty * 8 + i) * 512 + n0 + tx * 8;
        float4 o;
        o.x = acc[i][0] + bia[nc0 + tx * 8 + 0];
        o.y = acc[i][1] + bia[nc0 + tx * 8 + 1];
        o.z = acc[i][2] + bia[nc0 + tx * 8 + 2];
        o.w = acc[i][3] + bia[nc0 + tx * 8 + 3];
        *(float4*)&Cout[rbase] = o;
        o.x = acc[i][4] + bia[nc0 + tx * 8 + 4];
        o.y = acc[i][5] + bia[nc0 + tx * 8 + 5];
        o.z = acc[i][6] + bia[nc0 + tx * 8 + 6];
        o.w = acc[i][7] + bia[nc0 + tx * 8 + 7];
        *(float4*)&Cout[rbase + 4] = o;
    }
}

// ---------------------------------------------------------------------------
// LSTM recurrence, column-split. 256 blocks (batch x dir) x 256 threads.
// Wave w owns h-columns [w*16, w*16+16); lane = gate*16 + colLocal.
// Each lane: z[gate][col] = x + sum_k h[k] * U[k][gate*64+col]  (64 FMA).
// Gate nonlinearities parallel across lane groups; i/f/g/o combined
// INTRA-WAVE via 3 shfl_xor; c replicated in the 4 gate lanes of a column.
// Cross-wave traffic = 64 h floats via double-buffered LDS: ONE barrier/step.
// xz: [B*T][512] (dir offset 256). hout: [B*T][128] (fwd 0-63, bwd 64-127).
// ---------------------------------------------------------------------------
__global__ __launch_bounds__(256) void lstm_rec_cs(
    const float* __restrict__ xz, const float* __restrict__ Uf,
    const float* __restrict__ Ub, float* __restrict__ hout)
{
    const int b   = blockIdx.x & 127;
    const int dir = blockIdx.x >> 7;
    const int tid = threadIdx.x;
    const int w    = tid >> 6;          // wave 0..3
    const int lane = tid & 63;
    const int gate = lane >> 4;         // 0:i 1:f 2:g 3:o
    const int colL = lane & 15;
    const int col  = w * 16 + colL;     // h column 0..63
    const float* U = dir ? Ub : Uf;

    __shared__ float hbuf[2][64];

    // U column for this (gate, col): 64 VGPRs
    const int gcol = gate * 64 + col;
    float u[64];
    #pragma unroll
    for (int k = 0; k < 64; ++k) u[k] = U[(size_t)k * 256 + gcol];

    if (tid < 64) hbuf[0][tid] = 0.f;
    float c = 0.f;
    __syncthreads();

    const float* xzb = xz + (size_t)b * TT * 512 + (size_t)dir * 256 + gcol;
    float*       hob = hout + (size_t)b * TT * 128 + (size_t)dir * 64 + col;

    int trow = dir ? (TT - 1) : 0;
    const int tstep = dir ? -1 : 1;
    float xc = xzb[(size_t)trow * 512];
    int p = 0;

    for (int s = 0; s < TT; ++s) {
        const int trn = trow + tstep;
        float xn = 0.f;
        if (s + 1 < TT) xn = xzb[(size_t)trn * 512];   // prefetch next x

        // z = x + U[:,gcol] . h   (broadcast float4 reads, 4 partial accs)
        float a0 = 0.f, a1 = 0.f, a2 = 0.f, a3 = 0.f;
        #pragma unroll
        for (int k4 = 0; k4 < 64; k4 += 4) {
            const float4 hv = *(const float4*)&hbuf[p][k4];
            a0 = __fmaf_rn(hv.x, u[k4 + 0], a0);
            a1 = __fmaf_rn(hv.y, u[k4 + 1], a1);
            a2 = __fmaf_rn(hv.z, u[k4 + 2], a2);
            a3 = __fmaf_rn(hv.w, u[k4 + 3], a3);
        }
        const float z = xc + ((a0 + a1) + (a2 + a3));

        // own gate's activation (relu for gate 2, sigmoid otherwise)
        const float a = (gate == 2) ? fmaxf(z, 0.f) : sigf(z);

        // intra-wave all-gather of the 4 gate activations for this column.
        // sources: a: gate g, b0: g^1, b1: g^2, b2: g^3
        const float b0 = __shfl_xor(a, 16);
        const float b1 = __shfl_xor(a, 32);
        const float b2 = __shfl_xor(b0, 32);
        const float ai = (gate == 0) ? a : (gate == 1) ? b0 : (gate == 2) ? b1 : b2;
        const float af = (gate == 1) ? a : (gate == 0) ? b0 : (gate == 3) ? b1 : b2;
        const float ag = (gate == 2) ? a : (gate == 3) ? b0 : (gate == 0) ? b1 : b2;
        const float ao = (gate == 3) ? a : (gate == 2) ? b0 : (gate == 1) ? b1 : b2;

        // replicated state update (all 4 gate lanes of a column agree)
        c = af * c + ai * ag;            // ag already relu'd
        const float h = ao * fmaxf(c, 0.f);

        if (gate == 0) {                 // one writer per column
            hbuf[p ^ 1][col] = h;
            hob[(size_t)trow * 128] = h;
        }
        __syncthreads();                 // h ready for all waves; WAR safe via parity

        xc = xn;
        trow = trn;
        p ^= 1;
    }
}

// ---------------------------------------------------------------------------
// Dense + softmax: out[m][c] = softmax_c( h2[m][:] @ Wd[:,c] + bd[c] )
// ---------------------------------------------------------------------------
__global__ __launch_bounds__(256) void dense_softmax(
    const float* __restrict__ h2, const float* __restrict__ Wd,
    const float* __restrict__ bd, float* __restrict__ out)
{
    __shared__ float Wl[128 * 45];
    __shared__ float bl[48];
    __shared__ float hrow[4][128];
    const int tid = threadIdx.x;
    for (int i = tid; i < 128 * 45; i += 256) Wl[i] = Wd[i];
    if (tid < 45) bl[tid] = bd[tid];
    __syncthreads();

    const int w = tid >> 6, l = tid & 63;
    const size_t row0 = (size_t)blockIdx.x * 64;
    for (int rr = 0; rr < 16; ++rr) {
        const size_t m = row0 + (size_t)rr * 4 + w;
        const float2 hv = *(const float2*)&h2[m * 128 + l * 2];
        hrow[w][l * 2] = hv.x;
        hrow[w][l * 2 + 1] = hv.y;
        __syncthreads();
        float lg = -3.0e38f;
        if (l < CC) {
            lg = bl[l];
            #pragma unroll 8
            for (int k = 0; k < 128; ++k) lg = __fmaf_rn(hrow[w][k], Wl[k * 45 + l], lg);
        }
        float mx = lg;
        #pragma unroll
        for (int off = 32; off >= 1; off >>= 1) mx = fmaxf(mx, __shfl_xor(mx, off));
        const float e = (l < CC) ? __expf(lg - mx) : 0.f;
        float sm = e;
        #pragma unroll
        for (int off = 32; off >= 1; off >>= 1) sm += __shfl_xor(sm, off);
        if (l < CC) out[m * 45 + l] = e / sm;
        __syncthreads();
    }
}

// ---------------------------------------------------------------------------
extern "C" void kernel_launch(void* const* d_in, const int* in_sizes, int n_in,
                              void* d_out, int out_size, void* d_ws, size_t ws_size,
                              hipStream_t stream)
{
    const float* x   = (const float*)d_in[0];
    const float* W1f = (const float*)d_in[1];
    const float* U1f = (const float*)d_in[2];
    const float* b1f = (const float*)d_in[3];
    const float* W1b = (const float*)d_in[4];
    const float* U1b = (const float*)d_in[5];
    const float* b1b = (const float*)d_in[6];
    const float* W2f = (const float*)d_in[7];
    const float* U2f = (const float*)d_in[8];
    const float* b2f = (const float*)d_in[9];
    const float* W2b = (const float*)d_in[10];
    const float* U2b = (const float*)d_in[11];
    const float* b2b = (const float*)d_in[12];
    const float* Wd  = (const float*)d_in[13];
    const float* bd  = (const float*)d_in[14];

    // Workspace layout (160 MiB):
    //   xz : 65536 x 512 f32 = 128 MiB   (reused by layer 1 and layer 2)
    //   h  : 65536 x 128 f32 =  32 MiB   (h1, then overwritten by h2)
    float* xz = (float*)d_ws;
    float* h  = (float*)((char*)d_ws + (size_t)65536 * 512 * 4);

    const dim3 gemm_grid(512, 4);      // 65536/128 m-tiles, 512/128 n-tiles
    const dim3 rec_grid(256);          // 128 batch x 2 directions
    const dim3 dense_grid(1024);       // 65536/64 rows

    // Layer 1
    gemm_xz<<<gemm_grid, dim3(256), 0, stream>>>(x, W1f, W1b, b1f, b1b, xz);
    lstm_rec_cs<<<rec_grid, dim3(256), 0, stream>>>(xz, U1f, U1b, h);
    // Layer 2
    gemm_xz<<<gemm_grid, dim3(256), 0, stream>>>(h, W2f, W2b, b2f, b2b, xz);
    lstm_rec_cs<<<rec_grid, dim3(256), 0, stream>>>(xz, U2f, U2b, h);
    // Head
    dense_softmax<<<dense_grid, dim3(256), 0, stream>>>(h, Wd, bd, (float*)d_out);
}